// Round 1
// baseline (7002.187 us; speedup 1.0000x reference)
//
#include <hip/hip_runtime.h>
#include <math.h>
#include <stdint.h>
#include <stddef.h>

typedef _Float16 f16;
typedef __attribute__((ext_vector_type(4))) _Float16 f16x4;
typedef __attribute__((ext_vector_type(8))) _Float16 f16x8;
typedef __attribute__((ext_vector_type(4))) float f32x4;

#define MFMA(a, b, c) __builtin_amdgcn_mfma_f32_16x16x32_f16((a), (b), (c), 0, 0, 0)

#define LO_SCALE 4096.0f
#define LO_INV (1.0f / 4096.0f)
#define NBLK_GRU 192

// ===================== fp32 -> (hi, lo*4096) f16 split =====================
__global__ __launch_bounds__(256) void k_split(const float* __restrict__ src,
                                               f16* __restrict__ hi,
                                               f16* __restrict__ lo, int n4) {
  int idx = blockIdx.x * 256 + threadIdx.x;
  if (idx >= n4) return;
  float4 v = ((const float4*)src)[idx];
  float xs[4] = {v.x, v.y, v.z, v.w};
  f16x4 hv, lv;
#pragma unroll
  for (int e = 0; e < 4; ++e) {
    f16 h = (f16)xs[e];
    hv[e] = h;
    lv[e] = (f16)((xs[e] - (float)h) * LO_SCALE);
  }
  ((f16x4*)hi)[idx] = hv;
  ((f16x4*)lo)[idx] = lv;
}

// ===================== big GEMM: xg0 = x @ Wih0^T + bih0 =====================
__global__ __launch_bounds__(256) void k_gemm_xg0(const float* __restrict__ X,
                                                  const float* __restrict__ W,
                                                  const float* __restrict__ bih,
                                                  float* __restrict__ XG) {
  __shared__ f16 Ah[128 * 40];
  __shared__ f16 Al[128 * 40];
  __shared__ f16 Bh[64 * 40];
  __shared__ f16 Bl[64 * 40];

  const int m0 = blockIdx.x * 128;
  const int g0 = blockIdx.y * 64;
  const int tid = threadIdx.x;
  const int lane = tid & 63, wave = tid >> 6;
  const int wm = (wave & 1) * 64, wn = (wave >> 1) * 32;
  const int fr = lane & 15, fk = (lane >> 4) * 8;

  const int ar = tid >> 1, akc = (tid & 1) * 16;
  const int br = tid >> 2, bkc = (tid & 3) * 8;
  const float* Xp = X + (size_t)(m0 + ar) * 2048 + akc;
  const float* Wp = W + (size_t)(g0 + br) * 2048 + bkc;
  f16* ahw = Ah + ar * 40 + akc;
  f16* alw = Al + ar * 40 + akc;
  f16* bhw = Bh + br * 40 + bkc;
  f16* blw = Bl + br * 40 + bkc;

  const f32x4 z4 = {0.f, 0.f, 0.f, 0.f};
  f32x4 acc1[4][2], acc2[4][2];
#pragma unroll
  for (int mi = 0; mi < 4; ++mi)
#pragma unroll
    for (int ni = 0; ni < 2; ++ni) {
      acc1[mi][ni] = z4;
      acc2[mi][ni] = z4;
    }

  for (int kb = 0; kb < 2048; kb += 32) {
    {
      const float4* p = (const float4*)(Xp + kb);
#pragma unroll
      for (int q = 0; q < 2; ++q) {
        float4 u = p[2 * q], w2 = p[2 * q + 1];
        float xs[8] = {u.x, u.y, u.z, u.w, w2.x, w2.y, w2.z, w2.w};
        f16x8 hv, lv;
#pragma unroll
        for (int e = 0; e < 8; ++e) {
          f16 h = (f16)xs[e];
          hv[e] = h;
          lv[e] = (f16)((xs[e] - (float)h) * LO_SCALE);
        }
        ((f16x8*)ahw)[q] = hv;
        ((f16x8*)alw)[q] = lv;
      }
    }
    {
      const float4* p = (const float4*)(Wp + kb);
      float4 u = p[0], w2 = p[1];
      float xs[8] = {u.x, u.y, u.z, u.w, w2.x, w2.y, w2.z, w2.w};
      f16x8 hv, lv;
#pragma unroll
      for (int e = 0; e < 8; ++e) {
        f16 h = (f16)xs[e];
        hv[e] = h;
        lv[e] = (f16)((xs[e] - (float)h) * LO_SCALE);
      }
      *(f16x8*)bhw = hv;
      *(f16x8*)blw = lv;
    }
    __syncthreads();

    f16x8 a_h[4], a_l[4], b_h[2], b_l[2];
#pragma unroll
    for (int mi = 0; mi < 4; ++mi) {
      int r = wm + mi * 16 + fr;
      a_h[mi] = *(const f16x8*)&Ah[r * 40 + fk];
      a_l[mi] = *(const f16x8*)&Al[r * 40 + fk];
    }
#pragma unroll
    for (int ni = 0; ni < 2; ++ni) {
      int r = wn + ni * 16 + fr;
      b_h[ni] = *(const f16x8*)&Bh[r * 40 + fk];
      b_l[ni] = *(const f16x8*)&Bl[r * 40 + fk];
    }
#pragma unroll
    for (int mi = 0; mi < 4; ++mi)
#pragma unroll
      for (int ni = 0; ni < 2; ++ni) {
        acc1[mi][ni] = MFMA(a_h[mi], b_h[ni], acc1[mi][ni]);
        acc2[mi][ni] = MFMA(a_l[mi], b_h[ni], acc2[mi][ni]);
        acc2[mi][ni] = MFMA(a_h[mi], b_l[ni], acc2[mi][ni]);
      }
    __syncthreads();
  }

#pragma unroll
  for (int mi = 0; mi < 4; ++mi)
#pragma unroll
    for (int ni = 0; ni < 2; ++ni) {
      int g = g0 + wn + ni * 16 + fr;
      float bias = bih[g];
#pragma unroll
      for (int v = 0; v < 4; ++v) {
        int m = m0 + wm + mi * 16 + (lane >> 4) * 4 + v;
        int b = m / 250;
        int t = m - b * 250;
        XG[((size_t)t * 256 + b) * 768 + g] =
            acc1[mi][ni][v] + acc2[mi][ni][v] * LO_INV + bias;
      }
    }
}

// ===================== device-wide barrier (monotonic counter) ==============
__device__ __forceinline__ void gbar(int* bar, int step) {
  __syncthreads();
  if (threadIdx.x == 0) {
    __threadfence();  // release: drain + make this block's writes visible
    __hip_atomic_fetch_add(bar, 1, __ATOMIC_RELEASE, __HIP_MEMORY_SCOPE_AGENT);
    const int tgt = NBLK_GRU * (step + 1);
    while (__hip_atomic_load(bar, __ATOMIC_RELAXED, __HIP_MEMORY_SCOPE_AGENT) <
           tgt)
      __builtin_amdgcn_s_sleep(2);
    __threadfence();  // acquire: invalidate stale cached lines
  }
  __syncthreads();
}

// ===================== persistent GRU kernel =====================
// grid = 192 blocks x 256 thr. blocks 0..63: layer0; 64..191: layer1.
// Layer0 block: (mg in 0..3)=64-sample group, (ug in 0..15)=16 units.
//   Whh0 hi/lo fragments register-resident (full K=256): 48 f16x8.
// Layer1 block: (sg in 0..7)=32-sample group, (ug in 0..15)=16 units.
//   wave pairs split K: wave&1 = K-half; Wih1+Whh1 hi/lo frags = 48 f16x8.
//   Partial sums combined through LDS.
// One device-wide barrier per timestep (250 barriers).
__global__ __launch_bounds__(256, 1) void k_gru_persist(
    const float* __restrict__ XG, const f16* __restrict__ Whh0h,
    const f16* __restrict__ Whh0l, const f16* __restrict__ Wih1h,
    const f16* __restrict__ Wih1l, const f16* __restrict__ Whh1h,
    const f16* __restrict__ Whh1l, const float* __restrict__ bhh0,
    const float* __restrict__ bih1, const float* __restrict__ bhh1,
    float* __restrict__ h0f, f16* __restrict__ h0h, f16* __restrict__ h0l,
    float* __restrict__ h1f, f16* __restrict__ h1h, f16* __restrict__ h1l,
    int* __restrict__ bar) {
  __shared__ float red[4][4][4][64];  // [wave][slot][v][lane] = 16 KB

  const int wg = blockIdx.x;
  const bool isL1 = wg >= 64;
  const int tid = threadIdx.x;
  const int lane = tid & 63, wave = tid >> 6;
  const int fr = lane & 15, fk = (lane >> 4) * 8;
  const f32x4 z4 = {0.f, 0.f, 0.f, 0.f};

  if (!isL1) {
    // ---------------- layer 0 ----------------
    const int id = wg;
    const int mg = id & 3, ug = id >> 2;
    const int s0 = mg * 64 + wave * 16;
    const int j0 = ug * 16;
    const size_t wrow = (size_t)(j0 + fr) * 256 + fk;
    f16x8 w0h[3][8], w0l[3][8];
#pragma unroll
    for (int g = 0; g < 3; ++g)
#pragma unroll
      for (int kk = 0; kk < 8; ++kk) {
        size_t off = (size_t)g * 65536 + wrow + kk * 32;
        w0h[g][kk] = *(const f16x8*)(Whh0h + off);
        w0l[g][kk] = *(const f16x8*)(Whh0l + off);
      }
    const int j = j0 + fr;
    const float b_r = bhh0[j], b_z = bhh0[256 + j], b_n = bhh0[512 + j];

    for (int iv = 0; iv < 250; ++iv) {
      const int rd = (iv + 1) & 1;
      const int wr2 = iv & 1;
      // prefetch epilogue inputs (hide latency under MFMA chain)
      float xg_[4][3], hp_[4];
#pragma unroll
      for (int v = 0; v < 4; ++v) {
        int si = s0 + (lane >> 4) * 4 + v;
        size_t xb = ((size_t)iv * 256 + si) * 768 + j;
        xg_[v][0] = XG[xb];
        xg_[v][1] = XG[xb + 256];
        xg_[v][2] = XG[xb + 512];
        hp_[v] = h0f[rd * 65536 + si * 256 + j];
      }
      const f16* ah = h0h + rd * 65536 + (size_t)(s0 + fr) * 256 + fk;
      const f16* al = h0l + rd * 65536 + (size_t)(s0 + fr) * 256 + fk;
      f32x4 a1[3], a2[3];
#pragma unroll
      for (int g = 0; g < 3; ++g) {
        a1[g] = z4;
        a2[g] = z4;
      }
#pragma unroll
      for (int kk = 0; kk < 8; ++kk) {
        f16x8 xh = *(const f16x8*)(ah + kk * 32);
        f16x8 xl = *(const f16x8*)(al + kk * 32);
#pragma unroll
        for (int g = 0; g < 3; ++g) {
          a1[g] = MFMA(xh, w0h[g][kk], a1[g]);
          a2[g] = MFMA(xl, w0h[g][kk], a2[g]);
          a2[g] = MFMA(xh, w0l[g][kk], a2[g]);
        }
      }
#pragma unroll
      for (int v = 0; v < 4; ++v) {
        int si = s0 + (lane >> 4) * 4 + v;
        float hr = a1[0][v] + a2[0][v] * LO_INV + b_r;
        float hz = a1[1][v] + a2[1][v] * LO_INV + b_z;
        float hn = a1[2][v] + a2[2][v] * LO_INV + b_n;
        float r = 1.f / (1.f + expf(-(xg_[v][0] + hr)));
        float z = 1.f / (1.f + expf(-(xg_[v][1] + hz)));
        float n = tanhf(xg_[v][2] + r * hn);
        float hnew = (1.f - z) * n + z * hp_[v];
        int ow = wr2 * 65536 + si * 256 + j;
        h0f[ow] = hnew;
        f16 hh = (f16)hnew;
        h0h[ow] = hh;
        h0l[ow] = (f16)((hnew - (float)hh) * LO_SCALE);
      }
      gbar(bar, iv);
    }
  } else {
    // ---------------- layer 1 ----------------
    const int id = wg - 64;
    const int sg = id & 7, ug = id >> 3;
    const int pairsel = wave >> 1;  // 16-sample subgroup within the 32
    const int khalf = wave & 1;     // K-half 0/1
    const int s0 = sg * 32 + pairsel * 16;
    const int j0 = ug * 16;
    const int kbase = khalf * 128;
    const size_t wrow = (size_t)(j0 + fr) * 256 + kbase + fk;
    f16x8 w1h[3][4], w1l[3][4], w2h[3][4], w2l[3][4];
#pragma unroll
    for (int g = 0; g < 3; ++g)
#pragma unroll
      for (int kk = 0; kk < 4; ++kk) {
        size_t off = (size_t)g * 65536 + wrow + kk * 32;
        w1h[g][kk] = *(const f16x8*)(Wih1h + off);
        w1l[g][kk] = *(const f16x8*)(Wih1l + off);
        w2h[g][kk] = *(const f16x8*)(Whh1h + off);
        w2l[g][kk] = *(const f16x8*)(Whh1l + off);
      }
    const int jj = j0 + fr;
    const float bi_r = bih1[jj], bi_z = bih1[256 + jj], bi_n = bih1[512 + jj];
    const float bh_r = bhh1[jj], bh_z = bhh1[256 + jj], bh_n = bhh1[512 + jj];
    const int w2i = wave ^ 1;

    for (int iv = 0; iv <= 250; ++iv) {
      if (iv >= 1) {
        const int rd = (iv + 1) & 1;  // slot of h0 state (iv-1)
        const int s2 = iv & 1;        // slot of h1 state (iv-2)
        const int wo = (iv + 1) & 1;  // write slot for h1 state (iv-1)
        float hp_[2];
#pragma unroll
        for (int u = 0; u < 2; ++u) {
          int si = s0 + (lane >> 4) * 4 + khalf * 2 + u;
          hp_[u] = h1f[s2 * 65536 + si * 256 + jj];
        }
        const f16* a0h =
            h0h + rd * 65536 + (size_t)(s0 + fr) * 256 + kbase + fk;
        const f16* a0l =
            h0l + rd * 65536 + (size_t)(s0 + fr) * 256 + kbase + fk;
        const f16* b0h =
            h1h + s2 * 65536 + (size_t)(s0 + fr) * 256 + kbase + fk;
        const f16* b0l =
            h1l + s2 * 65536 + (size_t)(s0 + fr) * 256 + kbase + fk;
        f32x4 P1[3], P2[3], Q1[3], Q2[3];
#pragma unroll
        for (int g = 0; g < 3; ++g) {
          P1[g] = z4;
          P2[g] = z4;
          Q1[g] = z4;
          Q2[g] = z4;
        }
#pragma unroll
        for (int kk = 0; kk < 4; ++kk) {
          f16x8 xh = *(const f16x8*)(a0h + kk * 32);
          f16x8 xl = *(const f16x8*)(a0l + kk * 32);
          f16x8 yh = *(const f16x8*)(b0h + kk * 32);
          f16x8 yl = *(const f16x8*)(b0l + kk * 32);
#pragma unroll
          for (int g = 0; g < 3; ++g) {
            P1[g] = MFMA(xh, w1h[g][kk], P1[g]);
            P2[g] = MFMA(xl, w1h[g][kk], P2[g]);
            P2[g] = MFMA(xh, w1l[g][kk], P2[g]);
            Q1[g] = MFMA(yh, w2h[g][kk], Q1[g]);
            Q2[g] = MFMA(yl, w2h[g][kk], Q2[g]);
            Q2[g] = MFMA(yh, w2l[g][kk], Q2[g]);
          }
        }
        // combine K-halves through LDS. r,z gates merge x+h parts;
        // n gate keeps x-part (slot2) and h-part (slot3) separate (r*hn).
#pragma unroll
        for (int v = 0; v < 4; ++v) {
          red[wave][0][v][lane] =
              P1[0][v] + P2[0][v] * LO_INV + Q1[0][v] + Q2[0][v] * LO_INV;
          red[wave][1][v][lane] =
              P1[1][v] + P2[1][v] * LO_INV + Q1[1][v] + Q2[1][v] * LO_INV;
          red[wave][2][v][lane] = P1[2][v] + P2[2][v] * LO_INV;
          red[wave][3][v][lane] = Q1[2][v] + Q2[2][v] * LO_INV;
        }
        __syncthreads();
#pragma unroll
        for (int u = 0; u < 2; ++u) {
          int v = khalf * 2 + u;
          int si = s0 + (lane >> 4) * 4 + v;
          float sr = red[wave][0][v][lane] + red[w2i][0][v][lane] + bi_r + bh_r;
          float sz = red[wave][1][v][lane] + red[w2i][1][v][lane] + bi_z + bh_z;
          float xn = red[wave][2][v][lane] + red[w2i][2][v][lane] + bi_n;
          float hn = red[wave][3][v][lane] + red[w2i][3][v][lane] + bh_n;
          float r = 1.f / (1.f + expf(-sr));
          float z = 1.f / (1.f + expf(-sz));
          float n = tanhf(xn + r * hn);
          float hnew = (1.f - z) * n + z * hp_[u];
          int ow = wo * 65536 + si * 256 + jj;
          h1f[ow] = hnew;
          f16 hh = (f16)hnew;
          h1h[ow] = hh;
          h1l[ow] = (f16)((hnew - (float)hh) * LO_SCALE);
        }
      }
      if (iv < 250) gbar(bar, iv);
    }
  }
}

// ===================== head =====================
__global__ __launch_bounds__(256) void k_head(
    const f16* __restrict__ hh, const f16* __restrict__ hl,
    const f16* __restrict__ Wah, const f16* __restrict__ Wal,
    const f16* __restrict__ Wfh, const f16* __restrict__ Wfl,
    const float* __restrict__ ba, const float* __restrict__ bf,
    float* __restrict__ att, float* __restrict__ logit) {
  const int mat = blockIdx.z;
  const f16* Wh = mat ? Wfh : Wah;
  const f16* Wl = mat ? Wfl : Wal;
  const float* bias = mat ? bf : ba;
  float* outp = mat ? logit : att;
  const int n0 = blockIdx.x * 64;
  const int lane = threadIdx.x & 63, wave = threadIdx.x >> 6;
  const int s0 = blockIdx.y * 64 + wave * 16;
  const int fr = lane & 15, fk = (lane >> 4) * 8;
  const f16* ahp = hh + (size_t)(s0 + fr) * 256 + fk;
  const f16* alp = hl + (size_t)(s0 + fr) * 256 + fk;
  const f32x4 z4 = {0.f, 0.f, 0.f, 0.f};
  f32x4 c1[4], c2[4];
#pragma unroll
  for (int ni = 0; ni < 4; ++ni) {
    c1[ni] = z4;
    c2[ni] = z4;
  }
#pragma unroll 2
  for (int k = 0; k < 256; k += 32) {
    f16x8 xh = *(const f16x8*)(ahp + k);
    f16x8 xl = *(const f16x8*)(alp + k);
#pragma unroll
    for (int ni = 0; ni < 4; ++ni) {
      const f16* bp = Wh + (size_t)(n0 + ni * 16 + fr) * 256 + k + fk;
      const f16* bq = Wl + (size_t)(n0 + ni * 16 + fr) * 256 + k + fk;
      f16x8 bh = *(const f16x8*)bp;
      f16x8 bl = *(const f16x8*)bq;
      c1[ni] = MFMA(xh, bh, c1[ni]);
      c2[ni] = MFMA(xl, bh, c2[ni]);
      c2[ni] = MFMA(xh, bl, c2[ni]);
    }
  }
#pragma unroll
  for (int ni = 0; ni < 4; ++ni) {
    int c = n0 + ni * 16 + fr;
    float b = bias[c];
#pragma unroll
    for (int v = 0; v < 4; ++v) {
      int si = s0 + (lane >> 4) * 4 + v;
      float val = c1[ni][v] + c2[ni][v] * LO_INV + b;
      float sg = 1.f / (1.f + expf(-val));
      outp[(size_t)si * 2048 + c] = mat ? val * sg : sg;
    }
  }
}

// ===================== portfolio: topk + softmax-mask-norm + rebalance ======
__global__ __launch_bounds__(256) void k_port(const float* __restrict__ att,
                                              const float* __restrict__ logit,
                                              float* __restrict__ out) {
  __shared__ float av[2048];
  __shared__ float wv[2048];
  __shared__ float ov[2048];
  __shared__ unsigned char sel[2048];
  __shared__ float ra[4], rb[4], rc[4];
  __shared__ float rvv[4];
  __shared__ int rii[4];

  const int s = blockIdx.x;
  const int tid = threadIdx.x;
  const int lane = tid & 63, wave = tid >> 6;
  const float UBv = 0.1f;

  float lmax = -INFINITY;
#pragma unroll
  for (int j = 0; j < 8; ++j) {
    int i = tid + j * 256;
    av[i] = att[(size_t)s * 2048 + i];
    float l = logit[(size_t)s * 2048 + i];
    wv[i] = l;
    sel[i] = 0;
    lmax = fmaxf(lmax, l);
  }
#pragma unroll
  for (int off = 32; off; off >>= 1) lmax = fmaxf(lmax, __shfl_down(lmax, off, 64));
  if (lane == 0) ra[wave] = lmax;
  __syncthreads();
  float M = fmaxf(fmaxf(ra[0], ra[1]), fmaxf(ra[2], ra[3]));
  float es = 0.f;
#pragma unroll
  for (int j = 0; j < 8; ++j) {
    int i = tid + j * 256;
    float e = expf(wv[i] - M);
    wv[i] = e;
    es += e;
  }
#pragma unroll
  for (int off = 32; off; off >>= 1) es += __shfl_down(es, off, 64);
  __syncthreads();
  if (lane == 0) ra[wave] = es;
  __syncthreads();
  float S = ra[0] + ra[1] + ra[2] + ra[3];
#pragma unroll
  for (int j = 0; j < 8; ++j) {
    int i = tid + j * 256;
    wv[i] = wv[i] / S;
  }
  __syncthreads();

  for (int it = 0; it < 50; ++it) {
    float bv = -INFINITY;
    int bi = 0x7fffffff;
#pragma unroll
    for (int j = 0; j < 8; ++j) {
      int i = tid + j * 256;
      float v = av[i];
      if (v > bv || (v == bv && i < bi)) {
        bv = v;
        bi = i;
      }
    }
#pragma unroll
    for (int off = 32; off; off >>= 1) {
      float o2 = __shfl_down(bv, off, 64);
      int oi = __shfl_down(bi, off, 64);
      if (o2 > bv || (o2 == bv && oi < bi)) {
        bv = o2;
        bi = oi;
      }
    }
    if (lane == 0) {
      rvv[wave] = bv;
      rii[wave] = bi;
    }
    __syncthreads();
    if (tid == 0) {
      float fb = rvv[0];
      int fi = rii[0];
#pragma unroll
      for (int w2 = 1; w2 < 4; ++w2)
        if (rvv[w2] > fb || (rvv[w2] == fb && rii[w2] < fi)) {
          fb = rvv[w2];
          fi = rii[w2];
        }
      av[fi] = -INFINITY;
      sel[fi] = 1;
    }
    __syncthreads();
  }

  float ms = 0.f;
#pragma unroll
  for (int j = 0; j < 8; ++j) {
    int i = tid + j * 256;
    float m_ = sel[i] ? wv[i] : 0.f;
    wv[i] = m_;
    ms += m_;
  }
#pragma unroll
  for (int off = 32; off; off >>= 1) ms += __shfl_down(ms, off, 64);
  if (lane == 0) rb[wave] = ms;
  __syncthreads();
  float MS = rb[0] + rb[1] + rb[2] + rb[3];
  float den0 = MS + 1e-8f;
#pragma unroll
  for (int j = 0; j < 8; ++j) {
    int i = tid + j * 256;
    float w0 = wv[i] / den0;
    ov[i] = w0;
    sel[i] = (w0 > 0.f) ? 1 : 0;
    wv[i] = fminf(fmaxf(w0, 0.f), UBv);
  }

  bool done = false;
  for (int it = 0; it < 32; ++it) {
    __syncthreads();
    float lft = 0.f, ns = 0.f, hn = 0.f;
#pragma unroll
    for (int j = 0; j < 8; ++j) {
      int i = tid + j * 256;
      float wi = wv[i];
      bool nm = sel[i] && (wi != UBv);
      lft += ov[i] - wi;
      if (nm) {
        ns += wi;
        hn = 1.f;
      }
    }
#pragma unroll
    for (int off = 32; off; off >>= 1) {
      lft += __shfl_down(lft, off, 64);
      ns += __shfl_down(ns, off, 64);
      hn += __shfl_down(hn, off, 64);
    }
    if (lane == 0) {
      ra[wave] = lft;
      rb[wave] = ns;
      rc[wave] = hn;
    }
    __syncthreads();
    float LFT = ra[0] + ra[1] + ra[2] + ra[3];
    float NS = rb[0] + rb[1] + rb[2] + rb[3];
    bool has_nom = (rc[0] + rc[1] + rc[2] + rc[3]) > 0.f;
    bool upd = (!done) && has_nom;
    float dn = (NS == 0.f) ? 1.f : NS;
    bool over = false;
    if (upd) {
      float ovf = 0.f;
#pragma unroll
      for (int j = 0; j < 8; ++j) {
        int i = tid + j * 256;
        float wi = wv[i];
        bool nm = sel[i] && (wi != UBv);
        float w1 = wi + (nm ? (LFT * wi) / dn : 0.f);
        wv[i] = w1;
        ov[i] = w1;
        if (w1 > UBv) ovf = 1.f;
      }
#pragma unroll
      for (int off = 32; off; off >>= 1) ovf += __shfl_down(ovf, off, 64);
      __syncthreads();
      if (lane == 0) rc[wave] = ovf;
      __syncthreads();
      over = (rc[0] + rc[1] + rc[2] + rc[3]) > 0.f;
      if (over) {
#pragma unroll
        for (int j = 0; j < 8; ++j) {
          int i = tid + j * 256;
          wv[i] = fminf(fmaxf(wv[i], 0.f), UBv);
        }
      }
    }
    done = done || (!has_nom) || (upd && !over);
  }
  __syncthreads();
#pragma unroll
  for (int j = 0; j < 8; ++j) {
    int i = tid + j * 256;
    out[(size_t)s * 2048 + i] = wv[i];
  }
}

// ===================== launch =====================
extern "C" void kernel_launch(void* const* d_in, const int* in_sizes, int n_in,
                              void* d_out, int out_size, void* d_ws,
                              size_t ws_size, hipStream_t stream) {
  (void)in_sizes;
  (void)n_in;
  (void)out_size;
  (void)ws_size;
  const float* x = (const float*)d_in[0];
  const float* Wih0 = (const float*)d_in[1];
  const float* Whh0 = (const float*)d_in[2];
  const float* bih0 = (const float*)d_in[3];
  const float* bhh0 = (const float*)d_in[4];
  const float* Wih1 = (const float*)d_in[5];
  const float* Whh1 = (const float*)d_in[6];
  const float* bih1 = (const float*)d_in[7];
  const float* bhh1 = (const float*)d_in[8];
  const float* Wa = (const float*)d_in[9];
  const float* ba = (const float*)d_in[10];
  const float* Wf = (const float*)d_in[11];
  const float* bf = (const float*)d_in[12];

  char* p = (char*)d_ws;
  auto alloc = [&](size_t bytes) {
    char* q = p;
    p += (bytes + 255) & ~(size_t)255;
    return q;
  };
  float* XG = (float*)alloc((size_t)250 * 256 * 768 * 4);  // 196.6 MB
  f16* Whh0h = (f16*)alloc(768 * 256 * 2);
  f16* Whh0l = (f16*)alloc(768 * 256 * 2);
  f16* Wih1h = (f16*)alloc(768 * 256 * 2);
  f16* Wih1l = (f16*)alloc(768 * 256 * 2);
  f16* Whh1h = (f16*)alloc(768 * 256 * 2);
  f16* Whh1l = (f16*)alloc(768 * 256 * 2);
  f16* Wah = (f16*)alloc(2048 * 256 * 2);
  f16* Wal = (f16*)alloc(2048 * 256 * 2);
  f16* Wfh = (f16*)alloc(2048 * 256 * 2);
  f16* Wfl = (f16*)alloc(2048 * 256 * 2);
  float* h0f = (float*)alloc(2 * 65536 * 4);
  f16* h0h = (f16*)alloc(2 * 65536 * 2);
  f16* h0l = (f16*)alloc(2 * 65536 * 2);
  float* h1f = (float*)alloc(2 * 65536 * 4);
  f16* h1h = (f16*)alloc(2 * 65536 * 2);
  f16* h1l = (f16*)alloc(2 * 65536 * 2);
  float* attb = (float*)alloc((size_t)256 * 2048 * 4);
  float* logitb = (float*)alloc((size_t)256 * 2048 * 4);
  int* bar = (int*)alloc(256);

  // zero h states (contiguous) + barrier counter
  hipMemsetAsync(h0f, 0, (size_t)2 * 65536 * 8 * 2, stream);
  hipMemsetAsync(bar, 0, 256, stream);

  k_split<<<192, 256, 0, stream>>>(Whh0, Whh0h, Whh0l, 768 * 256 / 4);
  k_split<<<192, 256, 0, stream>>>(Wih1, Wih1h, Wih1l, 768 * 256 / 4);
  k_split<<<192, 256, 0, stream>>>(Whh1, Whh1h, Whh1l, 768 * 256 / 4);
  k_split<<<512, 256, 0, stream>>>(Wa, Wah, Wal, 2048 * 256 / 4);
  k_split<<<512, 256, 0, stream>>>(Wf, Wfh, Wfl, 2048 * 256 / 4);

  k_gemm_xg0<<<dim3(500, 12), 256, 0, stream>>>(x, Wih0, bih0, XG);

  k_gru_persist<<<NBLK_GRU, 256, 0, stream>>>(
      XG, Whh0h, Whh0l, Wih1h, Wih1l, Whh1h, Whh1l, bhh0, bih1, bhh1, h0f, h0h,
      h0l, h1f, h1h, h1l, bar);

  // final h1 state (t=249) lives in slot 1
  k_head<<<dim3(32, 4, 2), 256, 0, stream>>>(h1h + 65536, h1l + 65536, Wah, Wal,
                                             Wfh, Wfl, ba, bf, attb, logitb);
  k_port<<<256, 256, 0, stream>>>(attb, logitb, (float*)d_out);
}

// Round 3
// 5167.873 us; speedup vs baseline: 1.3549x; 1.3549x over previous
//
#include <hip/hip_runtime.h>
#include <math.h>
#include <stdint.h>
#include <stddef.h>

typedef _Float16 f16;
typedef __attribute__((ext_vector_type(4))) _Float16 f16x4;
typedef __attribute__((ext_vector_type(8))) _Float16 f16x8;
typedef __attribute__((ext_vector_type(4))) float f32x4;

#define MFMA(a, b, c) __builtin_amdgcn_mfma_f32_16x16x32_f16((a), (b), (c), 0, 0, 0)

#define LO_SCALE 4096.0f
#define LO_INV (1.0f / 4096.0f)
#define NBLK_GRU 192

// ===================== fp32 -> (hi, lo*4096) f16 split =====================
__global__ __launch_bounds__(256) void k_split(const float* __restrict__ src,
                                               f16* __restrict__ hi,
                                               f16* __restrict__ lo, int n4) {
  int idx = blockIdx.x * 256 + threadIdx.x;
  if (idx >= n4) return;
  float4 v = ((const float4*)src)[idx];
  float xs[4] = {v.x, v.y, v.z, v.w};
  f16x4 hv, lv;
#pragma unroll
  for (int e = 0; e < 4; ++e) {
    f16 h = (f16)xs[e];
    hv[e] = h;
    lv[e] = (f16)((xs[e] - (float)h) * LO_SCALE);
  }
  ((f16x4*)hi)[idx] = hv;
  ((f16x4*)lo)[idx] = lv;
}

// ===================== big GEMM: xg0 = x @ Wih0^T + bih0 =====================
__global__ __launch_bounds__(256) void k_gemm_xg0(const float* __restrict__ X,
                                                  const float* __restrict__ W,
                                                  const float* __restrict__ bih,
                                                  float* __restrict__ XG) {
  __shared__ f16 Ah[128 * 40];
  __shared__ f16 Al[128 * 40];
  __shared__ f16 Bh[64 * 40];
  __shared__ f16 Bl[64 * 40];

  const int m0 = blockIdx.x * 128;
  const int g0 = blockIdx.y * 64;
  const int tid = threadIdx.x;
  const int lane = tid & 63, wave = tid >> 6;
  const int wm = (wave & 1) * 64, wn = (wave >> 1) * 32;
  const int fr = lane & 15, fk = (lane >> 4) * 8;

  const int ar = tid >> 1, akc = (tid & 1) * 16;
  const int br = tid >> 2, bkc = (tid & 3) * 8;
  const float* Xp = X + (size_t)(m0 + ar) * 2048 + akc;
  const float* Wp = W + (size_t)(g0 + br) * 2048 + bkc;
  f16* ahw = Ah + ar * 40 + akc;
  f16* alw = Al + ar * 40 + akc;
  f16* bhw = Bh + br * 40 + bkc;
  f16* blw = Bl + br * 40 + bkc;

  const f32x4 z4 = {0.f, 0.f, 0.f, 0.f};
  f32x4 acc1[4][2], acc2[4][2];
#pragma unroll
  for (int mi = 0; mi < 4; ++mi)
#pragma unroll
    for (int ni = 0; ni < 2; ++ni) {
      acc1[mi][ni] = z4;
      acc2[mi][ni] = z4;
    }

  for (int kb = 0; kb < 2048; kb += 32) {
    {
      const float4* p = (const float4*)(Xp + kb);
#pragma unroll
      for (int q = 0; q < 2; ++q) {
        float4 u = p[2 * q], w2 = p[2 * q + 1];
        float xs[8] = {u.x, u.y, u.z, u.w, w2.x, w2.y, w2.z, w2.w};
        f16x8 hv, lv;
#pragma unroll
        for (int e = 0; e < 8; ++e) {
          f16 h = (f16)xs[e];
          hv[e] = h;
          lv[e] = (f16)((xs[e] - (float)h) * LO_SCALE);
        }
        ((f16x8*)ahw)[q] = hv;
        ((f16x8*)alw)[q] = lv;
      }
    }
    {
      const float4* p = (const float4*)(Wp + kb);
      float4 u = p[0], w2 = p[1];
      float xs[8] = {u.x, u.y, u.z, u.w, w2.x, w2.y, w2.z, w2.w};
      f16x8 hv, lv;
#pragma unroll
      for (int e = 0; e < 8; ++e) {
        f16 h = (f16)xs[e];
        hv[e] = h;
        lv[e] = (f16)((xs[e] - (float)h) * LO_SCALE);
      }
      *(f16x8*)bhw = hv;
      *(f16x8*)blw = lv;
    }
    __syncthreads();

    f16x8 a_h[4], a_l[4], b_h[2], b_l[2];
#pragma unroll
    for (int mi = 0; mi < 4; ++mi) {
      int r = wm + mi * 16 + fr;
      a_h[mi] = *(const f16x8*)&Ah[r * 40 + fk];
      a_l[mi] = *(const f16x8*)&Al[r * 40 + fk];
    }
#pragma unroll
    for (int ni = 0; ni < 2; ++ni) {
      int r = wn + ni * 16 + fr;
      b_h[ni] = *(const f16x8*)&Bh[r * 40 + fk];
      b_l[ni] = *(const f16x8*)&Bl[r * 40 + fk];
    }
#pragma unroll
    for (int mi = 0; mi < 4; ++mi)
#pragma unroll
      for (int ni = 0; ni < 2; ++ni) {
        acc1[mi][ni] = MFMA(a_h[mi], b_h[ni], acc1[mi][ni]);
        acc2[mi][ni] = MFMA(a_l[mi], b_h[ni], acc2[mi][ni]);
        acc2[mi][ni] = MFMA(a_h[mi], b_l[ni], acc2[mi][ni]);
      }
    __syncthreads();
  }

#pragma unroll
  for (int mi = 0; mi < 4; ++mi)
#pragma unroll
    for (int ni = 0; ni < 2; ++ni) {
      int g = g0 + wn + ni * 16 + fr;
      float bias = bih[g];
#pragma unroll
      for (int v = 0; v < 4; ++v) {
        int m = m0 + wm + mi * 16 + (lane >> 4) * 4 + v;
        int b = m / 250;
        int t = m - b * 250;
        XG[((size_t)t * 256 + b) * 768 + g] =
            acc1[mi][ni][v] + acc2[mi][ni][v] * LO_INV + bias;
      }
    }
}

// ===================== flag-based device barrier (no RMW contention) ========
// bar layout: arrive[b] at bar[b*64] (256B padded lines), go at bar[NBLK*64].
// Arrival: per-block release store into own line. Master (block 0): threads
// 0..191 each poll one distinct line, then one store of `go`.
// Workers poll only `go`, then acquire-fence.
__device__ __forceinline__ void flagbar(int* bar, int step, bool waitGo) {
  __syncthreads();
  const int tid = threadIdx.x;
  if (tid == 0) {
    __builtin_amdgcn_fence(__ATOMIC_RELEASE, "agent");  // publish h writes
    __hip_atomic_store(bar + blockIdx.x * 64, step + 1, __ATOMIC_RELAXED,
                       __HIP_MEMORY_SCOPE_AGENT);
  }
  if (blockIdx.x == 0) {
    if (tid < NBLK_GRU) {
      while (__hip_atomic_load(bar + tid * 64, __ATOMIC_RELAXED,
                               __HIP_MEMORY_SCOPE_AGENT) <= step)
        __builtin_amdgcn_s_sleep(1);
    }
    __syncthreads();  // all arrivals observed before go-store
    if (tid == 0) {
      __hip_atomic_store(bar + NBLK_GRU * 64, step + 1, __ATOMIC_RELAXED,
                         __HIP_MEMORY_SCOPE_AGENT);
      __builtin_amdgcn_fence(__ATOMIC_ACQUIRE, "agent");  // refresh own caches
    }
  } else if (waitGo) {
    if (tid == 0) {
      while (__hip_atomic_load(bar + NBLK_GRU * 64, __ATOMIC_RELAXED,
                               __HIP_MEMORY_SCOPE_AGENT) <= step)
        __builtin_amdgcn_s_sleep(2);
      __builtin_amdgcn_fence(__ATOMIC_ACQUIRE, "agent");  // refresh caches
    }
  }
  __syncthreads();
}

// ===================== persistent GRU kernel =====================
// grid = 192 blocks x 256 thr. blocks 0..63: layer0; 64..191: layer1.
// One flag barrier per timestep (250 barriers). Weights register-resident.
__global__ __launch_bounds__(256, 1) void k_gru_persist(
    const float* __restrict__ XG, const f16* __restrict__ Whh0h,
    const f16* __restrict__ Whh0l, const f16* __restrict__ Wih1h,
    const f16* __restrict__ Wih1l, const f16* __restrict__ Whh1h,
    const f16* __restrict__ Whh1l, const float* __restrict__ bhh0,
    const float* __restrict__ bih1, const float* __restrict__ bhh1,
    float* __restrict__ h0f, f16* __restrict__ h0h, f16* __restrict__ h0l,
    float* __restrict__ h1f, f16* __restrict__ h1h, f16* __restrict__ h1l,
    int* __restrict__ bar) {
  __shared__ float red[4][4][4][64];  // [wave][slot][v][lane] = 16 KB

  const int wg = blockIdx.x;
  const bool isL1 = wg >= 64;
  const int tid = threadIdx.x;
  const int lane = tid & 63, wave = tid >> 6;
  const int fr = lane & 15, fk = (lane >> 4) * 8;
  const f32x4 z4 = {0.f, 0.f, 0.f, 0.f};

  if (!isL1) {
    // ---------------- layer 0 ----------------
    const int id = wg;
    const int mg = id & 3, ug = id >> 2;
    const int s0 = mg * 64 + wave * 16;
    const int j0 = ug * 16;
    const size_t wrow = (size_t)(j0 + fr) * 256 + fk;
    f16x8 w0h[3][8], w0l[3][8];
#pragma unroll
    for (int g = 0; g < 3; ++g)
#pragma unroll
      for (int kk = 0; kk < 8; ++kk) {
        size_t off = (size_t)g * 65536 + wrow + kk * 32;
        w0h[g][kk] = *(const f16x8*)(Whh0h + off);
        w0l[g][kk] = *(const f16x8*)(Whh0l + off);
      }
    const int j = j0 + fr;
    const float b_r = bhh0[j], b_z = bhh0[256 + j], b_n = bhh0[512 + j];

    for (int iv = 0; iv < 250; ++iv) {
      const int rd = (iv + 1) & 1;
      const int wr2 = iv & 1;
      // prefetch epilogue inputs (hide latency under MFMA chain)
      float xg_[4][3], hp_[4];
#pragma unroll
      for (int v = 0; v < 4; ++v) {
        int si = s0 + (lane >> 4) * 4 + v;
        size_t xb = ((size_t)iv * 256 + si) * 768 + j;
        xg_[v][0] = XG[xb];
        xg_[v][1] = XG[xb + 256];
        xg_[v][2] = XG[xb + 512];
        hp_[v] = h0f[rd * 65536 + si * 256 + j];
      }
      const f16* ah = h0h + rd * 65536 + (size_t)(s0 + fr) * 256 + fk;
      const f16* al = h0l + rd * 65536 + (size_t)(s0 + fr) * 256 + fk;
      f32x4 a1[3], a2[3];
#pragma unroll
      for (int g = 0; g < 3; ++g) {
        a1[g] = z4;
        a2[g] = z4;
      }
#pragma unroll
      for (int kk = 0; kk < 8; ++kk) {
        f16x8 xh = *(const f16x8*)(ah + kk * 32);
        f16x8 xl = *(const f16x8*)(al + kk * 32);
#pragma unroll
        for (int g = 0; g < 3; ++g) {
          a1[g] = MFMA(xh, w0h[g][kk], a1[g]);
          a2[g] = MFMA(xl, w0h[g][kk], a2[g]);
          a2[g] = MFMA(xh, w0l[g][kk], a2[g]);
        }
      }
#pragma unroll
      for (int v = 0; v < 4; ++v) {
        int si = s0 + (lane >> 4) * 4 + v;
        float hr = a1[0][v] + a2[0][v] * LO_INV + b_r;
        float hz = a1[1][v] + a2[1][v] * LO_INV + b_z;
        float hn = a1[2][v] + a2[2][v] * LO_INV + b_n;
        float r = 1.f / (1.f + expf(-(xg_[v][0] + hr)));
        float z = 1.f / (1.f + expf(-(xg_[v][1] + hz)));
        float n = tanhf(xg_[v][2] + r * hn);
        float hnew = (1.f - z) * n + z * hp_[v];
        int ow = wr2 * 65536 + si * 256 + j;
        h0f[ow] = hnew;
        f16 hh = (f16)hnew;
        h0h[ow] = hh;
        h0l[ow] = (f16)((hnew - (float)hh) * LO_SCALE);
      }
      // last L0 step: post arrival (L1 needs h0[249]) but skip go-wait
      flagbar(bar, iv, iv < 249);
    }
  } else {
    // ---------------- layer 1 ----------------
    const int id = wg - 64;
    const int sg = id & 7, ug = id >> 3;
    const int pairsel = wave >> 1;  // 16-sample subgroup within the 32
    const int khalf = wave & 1;     // K-half 0/1
    const int s0 = sg * 32 + pairsel * 16;
    const int j0 = ug * 16;
    const int kbase = khalf * 128;
    const size_t wrow = (size_t)(j0 + fr) * 256 + kbase + fk;
    f16x8 w1h[3][4], w1l[3][4], w2h[3][4], w2l[3][4];
#pragma unroll
    for (int g = 0; g < 3; ++g)
#pragma unroll
      for (int kk = 0; kk < 4; ++kk) {
        size_t off = (size_t)g * 65536 + wrow + kk * 32;
        w1h[g][kk] = *(const f16x8*)(Wih1h + off);
        w1l[g][kk] = *(const f16x8*)(Wih1l + off);
        w2h[g][kk] = *(const f16x8*)(Whh1h + off);
        w2l[g][kk] = *(const f16x8*)(Whh1l + off);
      }
    const int jj = j0 + fr;
    const float bi_r = bih1[jj], bi_z = bih1[256 + jj], bi_n = bih1[512 + jj];
    const float bh_r = bhh1[jj], bh_z = bhh1[256 + jj], bh_n = bhh1[512 + jj];
    const int w2i = wave ^ 1;

    for (int iv = 0; iv <= 250; ++iv) {
      if (iv >= 1) {
        const int rd = (iv + 1) & 1;  // slot of h0 state (iv-1)
        const int s2 = iv & 1;        // slot of h1 state (iv-2)
        const int wo = (iv + 1) & 1;  // write slot for h1 state (iv-1)
        float hp_[2];
#pragma unroll
        for (int u = 0; u < 2; ++u) {
          int si = s0 + (lane >> 4) * 4 + khalf * 2 + u;
          hp_[u] = h1f[s2 * 65536 + si * 256 + jj];
        }
        const f16* a0h =
            h0h + rd * 65536 + (size_t)(s0 + fr) * 256 + kbase + fk;
        const f16* a0l =
            h0l + rd * 65536 + (size_t)(s0 + fr) * 256 + kbase + fk;
        const f16* b0h =
            h1h + s2 * 65536 + (size_t)(s0 + fr) * 256 + kbase + fk;
        const f16* b0l =
            h1l + s2 * 65536 + (size_t)(s0 + fr) * 256 + kbase + fk;
        f32x4 P1[3], P2[3], Q1[3], Q2[3];
#pragma unroll
        for (int g = 0; g < 3; ++g) {
          P1[g] = z4;
          P2[g] = z4;
          Q1[g] = z4;
          Q2[g] = z4;
        }
#pragma unroll
        for (int kk = 0; kk < 4; ++kk) {
          f16x8 xh = *(const f16x8*)(a0h + kk * 32);
          f16x8 xl = *(const f16x8*)(a0l + kk * 32);
          f16x8 yh = *(const f16x8*)(b0h + kk * 32);
          f16x8 yl = *(const f16x8*)(b0l + kk * 32);
#pragma unroll
          for (int g = 0; g < 3; ++g) {
            P1[g] = MFMA(xh, w1h[g][kk], P1[g]);
            P2[g] = MFMA(xl, w1h[g][kk], P2[g]);
            P2[g] = MFMA(xh, w1l[g][kk], P2[g]);
            Q1[g] = MFMA(yh, w2h[g][kk], Q1[g]);
            Q2[g] = MFMA(yl, w2h[g][kk], Q2[g]);
            Q2[g] = MFMA(yh, w2l[g][kk], Q2[g]);
          }
        }
        // combine K-halves through LDS. r,z gates merge x+h parts;
        // n gate keeps x-part (slot2) and h-part (slot3) separate (r*hn).
#pragma unroll
        for (int v = 0; v < 4; ++v) {
          red[wave][0][v][lane] =
              P1[0][v] + P2[0][v] * LO_INV + Q1[0][v] + Q2[0][v] * LO_INV;
          red[wave][1][v][lane] =
              P1[1][v] + P2[1][v] * LO_INV + Q1[1][v] + Q2[1][v] * LO_INV;
          red[wave][2][v][lane] = P1[2][v] + P2[2][v] * LO_INV;
          red[wave][3][v][lane] = Q1[2][v] + Q2[2][v] * LO_INV;
        }
        __syncthreads();
#pragma unroll
        for (int u = 0; u < 2; ++u) {
          int v = khalf * 2 + u;
          int si = s0 + (lane >> 4) * 4 + v;
          float sr = red[wave][0][v][lane] + red[w2i][0][v][lane] + bi_r + bh_r;
          float sz = red[wave][1][v][lane] + red[w2i][1][v][lane] + bi_z + bh_z;
          float xn = red[wave][2][v][lane] + red[w2i][2][v][lane] + bi_n;
          float hn = red[wave][3][v][lane] + red[w2i][3][v][lane] + bh_n;
          float r = 1.f / (1.f + expf(-sr));
          float z = 1.f / (1.f + expf(-sz));
          float n = tanhf(xn + r * hn);
          float hnew = (1.f - z) * n + z * hp_[u];
          int ow = wo * 65536 + si * 256 + jj;
          h1f[ow] = hnew;
          f16 hh = (f16)hnew;
          h1h[ow] = hh;
          h1l[ow] = (f16)((hnew - (float)hh) * LO_SCALE);
        }
      }
      if (iv < 250) flagbar(bar, iv, true);
    }
  }
}

// ===================== head =====================
__global__ __launch_bounds__(256) void k_head(
    const f16* __restrict__ hh, const f16* __restrict__ hl,
    const f16* __restrict__ Wah, const f16* __restrict__ Wal,
    const f16* __restrict__ Wfh, const f16* __restrict__ Wfl,
    const float* __restrict__ ba, const float* __restrict__ bf,
    float* __restrict__ att, float* __restrict__ logit) {
  const int mat = blockIdx.z;
  const f16* Wh = mat ? Wfh : Wah;
  const f16* Wl = mat ? Wfl : Wal;
  const float* bias = mat ? bf : ba;
  float* outp = mat ? logit : att;
  const int n0 = blockIdx.x * 64;
  const int lane = threadIdx.x & 63, wave = threadIdx.x >> 6;
  const int s0 = blockIdx.y * 64 + wave * 16;
  const int fr = lane & 15, fk = (lane >> 4) * 8;
  const f16* ahp = hh + (size_t)(s0 + fr) * 256 + fk;
  const f16* alp = hl + (size_t)(s0 + fr) * 256 + fk;
  const f32x4 z4 = {0.f, 0.f, 0.f, 0.f};
  f32x4 c1[4], c2[4];
#pragma unroll
  for (int ni = 0; ni < 4; ++ni) {
    c1[ni] = z4;
    c2[ni] = z4;
  }
#pragma unroll 2
  for (int k = 0; k < 256; k += 32) {
    f16x8 xh = *(const f16x8*)(ahp + k);
    f16x8 xl = *(const f16x8*)(alp + k);
#pragma unroll
    for (int ni = 0; ni < 4; ++ni) {
      const f16* bp = Wh + (size_t)(n0 + ni * 16 + fr) * 256 + k + fk;
      const f16* bq = Wl + (size_t)(n0 + ni * 16 + fr) * 256 + k + fk;
      f16x8 bh = *(const f16x8*)bp;
      f16x8 bl = *(const f16x8*)bq;
      c1[ni] = MFMA(xh, bh, c1[ni]);
      c2[ni] = MFMA(xl, bh, c2[ni]);
      c2[ni] = MFMA(xh, bl, c2[ni]);
    }
  }
#pragma unroll
  for (int ni = 0; ni < 4; ++ni) {
    int c = n0 + ni * 16 + fr;
    float b = bias[c];
#pragma unroll
    for (int v = 0; v < 4; ++v) {
      int si = s0 + (lane >> 4) * 4 + v;
      float val = c1[ni][v] + c2[ni][v] * LO_INV + b;
      float sg = 1.f / (1.f + expf(-val));
      outp[(size_t)si * 2048 + c] = mat ? val * sg : sg;
    }
  }
}

// ===================== portfolio: topk + softmax-mask-norm + rebalance ======
__global__ __launch_bounds__(256) void k_port(const float* __restrict__ att,
                                              const float* __restrict__ logit,
                                              float* __restrict__ out) {
  __shared__ float av[2048];
  __shared__ float wv[2048];
  __shared__ float ov[2048];
  __shared__ unsigned char sel[2048];
  __shared__ float ra[4], rb[4], rc[4];
  __shared__ float rvv[4];
  __shared__ int rii[4];

  const int s = blockIdx.x;
  const int tid = threadIdx.x;
  const int lane = tid & 63, wave = tid >> 6;
  const float UBv = 0.1f;

  float lmax = -INFINITY;
#pragma unroll
  for (int j = 0; j < 8; ++j) {
    int i = tid + j * 256;
    av[i] = att[(size_t)s * 2048 + i];
    float l = logit[(size_t)s * 2048 + i];
    wv[i] = l;
    sel[i] = 0;
    lmax = fmaxf(lmax, l);
  }
#pragma unroll
  for (int off = 32; off; off >>= 1) lmax = fmaxf(lmax, __shfl_down(lmax, off, 64));
  if (lane == 0) ra[wave] = lmax;
  __syncthreads();
  float M = fmaxf(fmaxf(ra[0], ra[1]), fmaxf(ra[2], ra[3]));
  float es = 0.f;
#pragma unroll
  for (int j = 0; j < 8; ++j) {
    int i = tid + j * 256;
    float e = expf(wv[i] - M);
    wv[i] = e;
    es += e;
  }
#pragma unroll
  for (int off = 32; off; off >>= 1) es += __shfl_down(es, off, 64);
  __syncthreads();
  if (lane == 0) ra[wave] = es;
  __syncthreads();
  float S = ra[0] + ra[1] + ra[2] + ra[3];
#pragma unroll
  for (int j = 0; j < 8; ++j) {
    int i = tid + j * 256;
    wv[i] = wv[i] / S;
  }
  __syncthreads();

  for (int it = 0; it < 50; ++it) {
    float bv = -INFINITY;
    int bi = 0x7fffffff;
#pragma unroll
    for (int j = 0; j < 8; ++j) {
      int i = tid + j * 256;
      float v = av[i];
      if (v > bv || (v == bv && i < bi)) {
        bv = v;
        bi = i;
      }
    }
#pragma unroll
    for (int off = 32; off; off >>= 1) {
      float o2 = __shfl_down(bv, off, 64);
      int oi = __shfl_down(bi, off, 64);
      if (o2 > bv || (o2 == bv && oi < bi)) {
        bv = o2;
        bi = oi;
      }
    }
    if (lane == 0) {
      rvv[wave] = bv;
      rii[wave] = bi;
    }
    __syncthreads();
    if (tid == 0) {
      float fb = rvv[0];
      int fi = rii[0];
#pragma unroll
      for (int w2 = 1; w2 < 4; ++w2)
        if (rvv[w2] > fb || (rvv[w2] == fb && rii[w2] < fi)) {
          fb = rvv[w2];
          fi = rii[w2];
        }
      av[fi] = -INFINITY;
      sel[fi] = 1;
    }
    __syncthreads();
  }

  float ms = 0.f;
#pragma unroll
  for (int j = 0; j < 8; ++j) {
    int i = tid + j * 256;
    float m_ = sel[i] ? wv[i] : 0.f;
    wv[i] = m_;
    ms += m_;
  }
#pragma unroll
  for (int off = 32; off; off >>= 1) ms += __shfl_down(ms, off, 64);
  if (lane == 0) rb[wave] = ms;
  __syncthreads();
  float MS = rb[0] + rb[1] + rb[2] + rb[3];
  float den0 = MS + 1e-8f;
#pragma unroll
  for (int j = 0; j < 8; ++j) {
    int i = tid + j * 256;
    float w0 = wv[i] / den0;
    ov[i] = w0;
    sel[i] = (w0 > 0.f) ? 1 : 0;
    wv[i] = fminf(fmaxf(w0, 0.f), UBv);
  }

  bool done = false;
  for (int it = 0; it < 32; ++it) {
    __syncthreads();
    float lft = 0.f, ns = 0.f, hn = 0.f;
#pragma unroll
    for (int j = 0; j < 8; ++j) {
      int i = tid + j * 256;
      float wi = wv[i];
      bool nm = sel[i] && (wi != UBv);
      lft += ov[i] - wi;
      if (nm) {
        ns += wi;
        hn = 1.f;
      }
    }
#pragma unroll
    for (int off = 32; off; off >>= 1) {
      lft += __shfl_down(lft, off, 64);
      ns += __shfl_down(ns, off, 64);
      hn += __shfl_down(hn, off, 64);
    }
    if (lane == 0) {
      ra[wave] = lft;
      rb[wave] = ns;
      rc[wave] = hn;
    }
    __syncthreads();
    float LFT = ra[0] + ra[1] + ra[2] + ra[3];
    float NS = rb[0] + rb[1] + rb[2] + rb[3];
    bool has_nom = (rc[0] + rc[1] + rc[2] + rc[3]) > 0.f;
    bool upd = (!done) && has_nom;
    float dn = (NS == 0.f) ? 1.f : NS;
    bool over = false;
    if (upd) {
      float ovf = 0.f;
#pragma unroll
      for (int j = 0; j < 8; ++j) {
        int i = tid + j * 256;
        float wi = wv[i];
        bool nm = sel[i] && (wi != UBv);
        float w1 = wi + (nm ? (LFT * wi) / dn : 0.f);
        wv[i] = w1;
        ov[i] = w1;
        if (w1 > UBv) ovf = 1.f;
      }
#pragma unroll
      for (int off = 32; off; off >>= 1) ovf += __shfl_down(ovf, off, 64);
      __syncthreads();
      if (lane == 0) rc[wave] = ovf;
      __syncthreads();
      over = (rc[0] + rc[1] + rc[2] + rc[3]) > 0.f;
      if (over) {
#pragma unroll
        for (int j = 0; j < 8; ++j) {
          int i = tid + j * 256;
          wv[i] = fminf(fmaxf(wv[i], 0.f), UBv);
        }
      }
    }
    done = done || (!has_nom) || (upd && !over);
  }
  __syncthreads();
#pragma unroll
  for (int j = 0; j < 8; ++j) {
    int i = tid + j * 256;
    out[(size_t)s * 2048 + i] = wv[i];
  }
}

// ===================== launch =====================
extern "C" void kernel_launch(void* const* d_in, const int* in_sizes, int n_in,
                              void* d_out, int out_size, void* d_ws,
                              size_t ws_size, hipStream_t stream) {
  (void)in_sizes;
  (void)n_in;
  (void)out_size;
  (void)ws_size;
  const float* x = (const float*)d_in[0];
  const float* Wih0 = (const float*)d_in[1];
  const float* Whh0 = (const float*)d_in[2];
  const float* bih0 = (const float*)d_in[3];
  const float* bhh0 = (const float*)d_in[4];
  const float* Wih1 = (const float*)d_in[5];
  const float* Whh1 = (const float*)d_in[6];
  const float* bih1 = (const float*)d_in[7];
  const float* bhh1 = (const float*)d_in[8];
  const float* Wa = (const float*)d_in[9];
  const float* ba = (const float*)d_in[10];
  const float* Wf = (const float*)d_in[11];
  const float* bf = (const float*)d_in[12];

  char* p = (char*)d_ws;
  auto alloc = [&](size_t bytes) {
    char* q = p;
    p += (bytes + 255) & ~(size_t)255;
    return q;
  };
  float* XG = (float*)alloc((size_t)250 * 256 * 768 * 4);  // 196.6 MB
  f16* Whh0h = (f16*)alloc(768 * 256 * 2);
  f16* Whh0l = (f16*)alloc(768 * 256 * 2);
  f16* Wih1h = (f16*)alloc(768 * 256 * 2);
  f16* Wih1l = (f16*)alloc(768 * 256 * 2);
  f16* Whh1h = (f16*)alloc(768 * 256 * 2);
  f16* Whh1l = (f16*)alloc(768 * 256 * 2);
  f16* Wah = (f16*)alloc(2048 * 256 * 2);
  f16* Wal = (f16*)alloc(2048 * 256 * 2);
  f16* Wfh = (f16*)alloc(2048 * 256 * 2);
  f16* Wfl = (f16*)alloc(2048 * 256 * 2);
  float* h0f = (float*)alloc(2 * 65536 * 4);
  f16* h0h = (f16*)alloc(2 * 65536 * 2);
  f16* h0l = (f16*)alloc(2 * 65536 * 2);
  float* h1f = (float*)alloc(2 * 65536 * 4);
  f16* h1h = (f16*)alloc(2 * 65536 * 2);
  f16* h1l = (f16*)alloc(2 * 65536 * 2);
  float* attb = (float*)alloc((size_t)256 * 2048 * 4);
  float* logitb = (float*)alloc((size_t)256 * 2048 * 4);
  int* bar = (int*)alloc(64 * 1024);  // flag barrier: 193 padded slots

  // zero h states (contiguous) + barrier flags
  hipMemsetAsync(h0f, 0, (size_t)2 * 65536 * 8 * 2, stream);
  hipMemsetAsync(bar, 0, 64 * 1024, stream);

  k_split<<<192, 256, 0, stream>>>(Whh0, Whh0h, Whh0l, 768 * 256 / 4);
  k_split<<<192, 256, 0, stream>>>(Wih1, Wih1h, Wih1l, 768 * 256 / 4);
  k_split<<<192, 256, 0, stream>>>(Whh1, Whh1h, Whh1l, 768 * 256 / 4);
  k_split<<<512, 256, 0, stream>>>(Wa, Wah, Wal, 2048 * 256 / 4);
  k_split<<<512, 256, 0, stream>>>(Wf, Wfh, Wfl, 2048 * 256 / 4);

  k_gemm_xg0<<<dim3(500, 12), 256, 0, stream>>>(x, Wih0, bih0, XG);

  k_gru_persist<<<NBLK_GRU, 256, 0, stream>>>(
      XG, Whh0h, Whh0l, Wih1h, Wih1l, Whh1h, Whh1l, bhh0, bih1, bhh1, h0f, h0h,
      h0l, h1f, h1h, h1l, bar);

  // final h1 state (t=249) lives in slot 1
  k_head<<<dim3(32, 4, 2), 256, 0, stream>>>(h1h + 65536, h1l + 65536, Wah, Wal,
                                             Wfh, Wfl, ba, bf, attb, logitb);
  k_port<<<256, 256, 0, stream>>>(attb, logitb, (float*)d_out);
}

// Round 5
// 3802.990 us; speedup vs baseline: 1.8412x; 1.3589x over previous
//
#include <hip/hip_runtime.h>
#include <math.h>
#include <stdint.h>
#include <stddef.h>

typedef _Float16 f16;
typedef __attribute__((ext_vector_type(4))) _Float16 f16x4;
typedef __attribute__((ext_vector_type(8))) _Float16 f16x8;
typedef __attribute__((ext_vector_type(4))) float f32x4;

#define MFMA(a, b, c) __builtin_amdgcn_mfma_f32_16x16x32_f16((a), (b), (c), 0, 0, 0)

#define LO_SCALE 4096.0f
#define LO_INV (1.0f / 4096.0f)
#define NBLK_GRU 192

// ===================== fp32 -> (hi, lo*4096) f16 split =====================
__global__ __launch_bounds__(256) void k_split(const float* __restrict__ src,
                                               f16* __restrict__ hi,
                                               f16* __restrict__ lo, int n4) {
  int idx = blockIdx.x * 256 + threadIdx.x;
  if (idx >= n4) return;
  float4 v = ((const float4*)src)[idx];
  float xs[4] = {v.x, v.y, v.z, v.w};
  f16x4 hv, lv;
#pragma unroll
  for (int e = 0; e < 4; ++e) {
    f16 h = (f16)xs[e];
    hv[e] = h;
    lv[e] = (f16)((xs[e] - (float)h) * LO_SCALE);
  }
  ((f16x4*)hi)[idx] = hv;
  ((f16x4*)lo)[idx] = lv;
}

// ===================== big GEMM: xg0 = x @ Wih0^T + bih0 =====================
__global__ __launch_bounds__(256) void k_gemm_xg0(const float* __restrict__ X,
                                                  const float* __restrict__ W,
                                                  const float* __restrict__ bih,
                                                  float* __restrict__ XG) {
  __shared__ f16 Ah[128 * 40];
  __shared__ f16 Al[128 * 40];
  __shared__ f16 Bh[64 * 40];
  __shared__ f16 Bl[64 * 40];

  const int m0 = blockIdx.x * 128;
  const int g0 = blockIdx.y * 64;
  const int tid = threadIdx.x;
  const int lane = tid & 63, wave = tid >> 6;
  const int wm = (wave & 1) * 64, wn = (wave >> 1) * 32;
  const int fr = lane & 15, fk = (lane >> 4) * 8;

  const int ar = tid >> 1, akc = (tid & 1) * 16;
  const int br = tid >> 2, bkc = (tid & 3) * 8;
  const float* Xp = X + (size_t)(m0 + ar) * 2048 + akc;
  const float* Wp = W + (size_t)(g0 + br) * 2048 + bkc;
  f16* ahw = Ah + ar * 40 + akc;
  f16* alw = Al + ar * 40 + akc;
  f16* bhw = Bh + br * 40 + bkc;
  f16* blw = Bl + br * 40 + bkc;

  const f32x4 z4 = {0.f, 0.f, 0.f, 0.f};
  f32x4 acc1[4][2], acc2[4][2];
#pragma unroll
  for (int mi = 0; mi < 4; ++mi)
#pragma unroll
    for (int ni = 0; ni < 2; ++ni) {
      acc1[mi][ni] = z4;
      acc2[mi][ni] = z4;
    }

  for (int kb = 0; kb < 2048; kb += 32) {
    {
      const float4* p = (const float4*)(Xp + kb);
#pragma unroll
      for (int q = 0; q < 2; ++q) {
        float4 u = p[2 * q], w2 = p[2 * q + 1];
        float xs[8] = {u.x, u.y, u.z, u.w, w2.x, w2.y, w2.z, w2.w};
        f16x8 hv, lv;
#pragma unroll
        for (int e = 0; e < 8; ++e) {
          f16 h = (f16)xs[e];
          hv[e] = h;
          lv[e] = (f16)((xs[e] - (float)h) * LO_SCALE);
        }
        ((f16x8*)ahw)[q] = hv;
        ((f16x8*)alw)[q] = lv;
      }
    }
    {
      const float4* p = (const float4*)(Wp + kb);
      float4 u = p[0], w2 = p[1];
      float xs[8] = {u.x, u.y, u.z, u.w, w2.x, w2.y, w2.z, w2.w};
      f16x8 hv, lv;
#pragma unroll
      for (int e = 0; e < 8; ++e) {
        f16 h = (f16)xs[e];
        hv[e] = h;
        lv[e] = (f16)((xs[e] - (float)h) * LO_SCALE);
      }
      *(f16x8*)bhw = hv;
      *(f16x8*)blw = lv;
    }
    __syncthreads();

    f16x8 a_h[4], a_l[4], b_h[2], b_l[2];
#pragma unroll
    for (int mi = 0; mi < 4; ++mi) {
      int r = wm + mi * 16 + fr;
      a_h[mi] = *(const f16x8*)&Ah[r * 40 + fk];
      a_l[mi] = *(const f16x8*)&Al[r * 40 + fk];
    }
#pragma unroll
    for (int ni = 0; ni < 2; ++ni) {
      int r = wn + ni * 16 + fr;
      b_h[ni] = *(const f16x8*)&Bh[r * 40 + fk];
      b_l[ni] = *(const f16x8*)&Bl[r * 40 + fk];
    }
#pragma unroll
    for (int mi = 0; mi < 4; ++mi)
#pragma unroll
      for (int ni = 0; ni < 2; ++ni) {
        acc1[mi][ni] = MFMA(a_h[mi], b_h[ni], acc1[mi][ni]);
        acc2[mi][ni] = MFMA(a_l[mi], b_h[ni], acc2[mi][ni]);
        acc2[mi][ni] = MFMA(a_h[mi], b_l[ni], acc2[mi][ni]);
      }
    __syncthreads();
  }

#pragma unroll
  for (int mi = 0; mi < 4; ++mi)
#pragma unroll
    for (int ni = 0; ni < 2; ++ni) {
      int g = g0 + wn + ni * 16 + fr;
      float bias = bih[g];
#pragma unroll
      for (int v = 0; v < 4; ++v) {
        int m = m0 + wm + mi * 16 + (lane >> 4) * 4 + v;
        int b = m / 250;
        int t = m - b * 250;
        XG[((size_t)t * 256 + b) * 768 + g] =
            acc1[mi][ni][v] + acc2[mi][ni][v] * LO_INV + bias;
      }
    }
}

// ===================== coherent (cross-XCD) load/store helpers ==============
// Agent-scope relaxed atomics: loads/stores go to the coherence point, so no
// cache-maintenance fences are needed anywhere in the timestep loop.
__device__ __forceinline__ f16x8 cload(const f16* p) {
  union {
    unsigned long long q[2];
    f16x8 v;
  } u;
  const unsigned long long* pp = (const unsigned long long*)p;
  u.q[0] = __hip_atomic_load(pp, __ATOMIC_RELAXED, __HIP_MEMORY_SCOPE_AGENT);
  u.q[1] =
      __hip_atomic_load(pp + 1, __ATOMIC_RELAXED, __HIP_MEMORY_SCOPE_AGENT);
  return u.v;
}

// Lane-paired packed u32 coherent store of one (hi, lo) f16 pair.
// Adjacent lanes hold adjacent units j; even lane stores the hi-array word
// [j, j+1], odd lane stores the lo-array word [j-1, j].
__device__ __forceinline__ void cstore_pair(f16* hiArr, f16* loArr, size_t ow,
                                            int lane, f16 vh, f16 vl) {
  int me_h = (int)__builtin_bit_cast(unsigned short, vh);
  int me_l = (int)__builtin_bit_cast(unsigned short, vl);
  int nb_h = __shfl_xor(me_h, 1, 64);
  int nb_l = __shfl_xor(me_l, 1, 64);
  if ((lane & 1) == 0) {
    unsigned w = (unsigned)me_h | ((unsigned)nb_h << 16);
    __hip_atomic_store((unsigned*)(hiArr + ow), w, __ATOMIC_RELAXED,
                       __HIP_MEMORY_SCOPE_AGENT);
  } else {
    unsigned w = (unsigned)nb_l | ((unsigned)me_l << 16);
    __hip_atomic_store((unsigned*)(loArr + ow - 1), w, __ATOMIC_RELAXED,
                       __HIP_MEMORY_SCOPE_AGENT);
  }
}

// ===================== masterless per-group barrier =====================
// 4 independent sample groups; each has 48 blocks (16 L0 + 32 L1).
// Slot = grp*64 + rank (256B padded). Arrival: one relaxed agent store into
// own slot. Wait: threads 0..47 poll all 48 slots directly (no master, no
// go-flag). The vmcnt(0) drain at the preceding __syncthreads guarantees the
// coherent h-stores are globally visible before the arrival flag posts.
__device__ __forceinline__ void grpbar(int* bar, int grp, int rank, int step,
                                       bool doPoll) {
  __syncthreads();
  if (threadIdx.x == 0)
    __hip_atomic_store(bar + (grp * 64 + rank) * 64, step + 1, __ATOMIC_RELAXED,
                       __HIP_MEMORY_SCOPE_AGENT);
  if (doPoll) {
    if (threadIdx.x < 48) {
      while (__hip_atomic_load(bar + (grp * 64 + (int)threadIdx.x) * 64,
                               __ATOMIC_RELAXED,
                               __HIP_MEMORY_SCOPE_AGENT) <= step)
        __builtin_amdgcn_s_sleep(1);
    }
    __builtin_amdgcn_fence(__ATOMIC_ACQUIRE, "workgroup");  // compiler order
  }
  __syncthreads();
}

// ===================== persistent GRU kernel =====================
// grid = 192 blocks x 256 thr. blocks 0..63: layer0; 64..191: layer1.
// Weights register-resident; h f16 state via coherent atomics; per-group
// barrier per timestep.
__global__ __launch_bounds__(256, 1) void k_gru_persist(
    const float* __restrict__ XG, const f16* __restrict__ Whh0h,
    const f16* __restrict__ Whh0l, const f16* __restrict__ Wih1h,
    const f16* __restrict__ Wih1l, const f16* __restrict__ Whh1h,
    const f16* __restrict__ Whh1l, const float* __restrict__ bhh0,
    const float* __restrict__ bih1, const float* __restrict__ bhh1,
    float* __restrict__ h0f, f16* __restrict__ h0h, f16* __restrict__ h0l,
    float* __restrict__ h1f, f16* __restrict__ h1h, f16* __restrict__ h1l,
    int* __restrict__ bar) {
  __shared__ float red[4][4][4][64];  // [wave][slot][v][lane] = 16 KB

  const int wg = blockIdx.x;
  const bool isL1 = wg >= 64;
  const int tid = threadIdx.x;
  const int lane = tid & 63, wave = tid >> 6;
  const int fr = lane & 15, fk = (lane >> 4) * 8;
  const f32x4 z4 = {0.f, 0.f, 0.f, 0.f};

  if (!isL1) {
    // ---------------- layer 0 ----------------
    const int id = wg;
    const int mg = id & 3, ug = id >> 2;
    const int s0 = mg * 64 + wave * 16;
    const int j0 = ug * 16;
    const size_t wrow = (size_t)(j0 + fr) * 256 + fk;
    f16x8 w0h[3][8], w0l[3][8];
#pragma unroll
    for (int g = 0; g < 3; ++g)
#pragma unroll
      for (int kk = 0; kk < 8; ++kk) {
        size_t off = (size_t)g * 65536 + wrow + kk * 32;
        w0h[g][kk] = *(const f16x8*)(Whh0h + off);
        w0l[g][kk] = *(const f16x8*)(Whh0l + off);
      }
    const int j = j0 + fr;
    const float b_r = bhh0[j], b_z = bhh0[256 + j], b_n = bhh0[512 + j];

    for (int iv = 0; iv < 250; ++iv) {
      const int rd = (iv + 1) & 1;
      const int wr2 = iv & 1;
      // prefetch epilogue inputs (plain; XG stream + self-owned h0f)
      float xg_[4][3], hp_[4];
#pragma unroll
      for (int v = 0; v < 4; ++v) {
        int si = s0 + (lane >> 4) * 4 + v;
        size_t xb = ((size_t)iv * 256 + si) * 768 + j;
        xg_[v][0] = XG[xb];
        xg_[v][1] = XG[xb + 256];
        xg_[v][2] = XG[xb + 512];
        hp_[v] = h0f[rd * 65536 + si * 256 + j];
      }
      const f16* ah = h0h + rd * 65536 + (size_t)(s0 + fr) * 256 + fk;
      const f16* al = h0l + rd * 65536 + (size_t)(s0 + fr) * 256 + fk;
      // batched coherent fragment loads (issue all, then compute)
      f16x8 XH[8], XL[8];
#pragma unroll
      for (int kk = 0; kk < 8; ++kk) {
        XH[kk] = cload(ah + kk * 32);
        XL[kk] = cload(al + kk * 32);
      }
      f32x4 a1[3], a2[3];
#pragma unroll
      for (int g = 0; g < 3; ++g) {
        a1[g] = z4;
        a2[g] = z4;
      }
#pragma unroll
      for (int kk = 0; kk < 8; ++kk) {
#pragma unroll
        for (int g = 0; g < 3; ++g) {
          a1[g] = MFMA(XH[kk], w0h[g][kk], a1[g]);
          a2[g] = MFMA(XL[kk], w0h[g][kk], a2[g]);
          a2[g] = MFMA(XH[kk], w0l[g][kk], a2[g]);
        }
      }
#pragma unroll
      for (int v = 0; v < 4; ++v) {
        int si = s0 + (lane >> 4) * 4 + v;
        float hr = a1[0][v] + a2[0][v] * LO_INV + b_r;
        float hz = a1[1][v] + a2[1][v] * LO_INV + b_z;
        float hn = a1[2][v] + a2[2][v] * LO_INV + b_n;
        float r = 1.f / (1.f + expf(-(xg_[v][0] + hr)));
        float z = 1.f / (1.f + expf(-(xg_[v][1] + hz)));
        float n = tanhf(xg_[v][2] + r * hn);
        float hnew = (1.f - z) * n + z * hp_[v];
        size_t ow = (size_t)wr2 * 65536 + (size_t)si * 256 + j;
        h0f[ow] = hnew;  // self-owned: plain store
        f16 hh = (f16)hnew;
        f16 hl = (f16)((hnew - (float)hh) * LO_SCALE);
        cstore_pair(h0h, h0l, ow, lane, hh, hl);
      }
      // last L0 step: post arrival (L1 needs h0[249]) but skip the poll
      grpbar(bar, mg, ug, iv, iv < 249);
    }
  } else {
    // ---------------- layer 1 ----------------
    const int id = wg - 64;
    const int sg = id & 7, ug = id >> 3;
    const int mg = sg >> 1;
    const int rank = 16 + (sg & 1) * 16 + ug;  // 16..47, collision-free
    const int pairsel = wave >> 1;  // 16-sample subgroup within the 32
    const int khalf = wave & 1;     // K-half 0/1
    const int s0 = sg * 32 + pairsel * 16;
    const int j0 = ug * 16;
    const int kbase = khalf * 128;
    const size_t wrow = (size_t)(j0 + fr) * 256 + kbase + fk;
    f16x8 w1h[3][4], w1l[3][4], w2h[3][4], w2l[3][4];
#pragma unroll
    for (int g = 0; g < 3; ++g)
#pragma unroll
      for (int kk = 0; kk < 4; ++kk) {
        size_t off = (size_t)g * 65536 + wrow + kk * 32;
        w1h[g][kk] = *(const f16x8*)(Wih1h + off);
        w1l[g][kk] = *(const f16x8*)(Wih1l + off);
        w2h[g][kk] = *(const f16x8*)(Whh1h + off);
        w2l[g][kk] = *(const f16x8*)(Whh1l + off);
      }
    const int jj = j0 + fr;
    const float bi_r = bih1[jj], bi_z = bih1[256 + jj], bi_n = bih1[512 + jj];
    const float bh_r = bhh1[jj], bh_z = bhh1[256 + jj], bh_n = bhh1[512 + jj];
    const int w2i = wave ^ 1;

    for (int iv = 0; iv <= 250; ++iv) {
      if (iv >= 1) {
        const int rd = (iv + 1) & 1;  // slot of h0 state (iv-1)
        const int s2 = iv & 1;        // slot of h1 state (iv-2)
        const int wo = (iv + 1) & 1;  // write slot for h1 state (iv-1)
        float hp_[2];
#pragma unroll
        for (int u = 0; u < 2; ++u) {
          int si = s0 + (lane >> 4) * 4 + khalf * 2 + u;
          hp_[u] = h1f[s2 * 65536 + si * 256 + jj];  // self-owned: plain
        }
        const f16* a0h =
            h0h + rd * 65536 + (size_t)(s0 + fr) * 256 + kbase + fk;
        const f16* a0l =
            h0l + rd * 65536 + (size_t)(s0 + fr) * 256 + kbase + fk;
        const f16* b0h =
            h1h + s2 * 65536 + (size_t)(s0 + fr) * 256 + kbase + fk;
        const f16* b0l =
            h1l + s2 * 65536 + (size_t)(s0 + fr) * 256 + kbase + fk;
        // batched coherent fragment loads
        f16x8 XH[4], XL[4], YH[4], YL[4];
#pragma unroll
        for (int kk = 0; kk < 4; ++kk) {
          XH[kk] = cload(a0h + kk * 32);
          XL[kk] = cload(a0l + kk * 32);
          YH[kk] = cload(b0h + kk * 32);
          YL[kk] = cload(b0l + kk * 32);
        }
        f32x4 P1[3], P2[3], Q1[3], Q2[3];
#pragma unroll
        for (int g = 0; g < 3; ++g) {
          P1[g] = z4;
          P2[g] = z4;
          Q1[g] = z4;
          Q2[g] = z4;
        }
#pragma unroll
        for (int kk = 0; kk < 4; ++kk) {
#pragma unroll
          for (int g = 0; g < 3; ++g) {
            P1[g] = MFMA(XH[kk], w1h[g][kk], P1[g]);
            P2[g] = MFMA(XL[kk], w1h[g][kk], P2[g]);
            P2[g] = MFMA(XH[kk], w1l[g][kk], P2[g]);
            Q1[g] = MFMA(YH[kk], w2h[g][kk], Q1[g]);
            Q2[g] = MFMA(YL[kk], w2h[g][kk], Q2[g]);
            Q2[g] = MFMA(YH[kk], w2l[g][kk], Q2[g]);
          }
        }
        // combine K-halves through LDS. r,z gates merge x+h parts;
        // n gate keeps x-part (slot2) and h-part (slot3) separate (r*hn).
#pragma unroll
        for (int v = 0; v < 4; ++v) {
          red[wave][0][v][lane] =
              P1[0][v] + P2[0][v] * LO_INV + Q1[0][v] + Q2[0][v] * LO_INV;
          red[wave][1][v][lane] =
              P1[1][v] + P2[1][v] * LO_INV + Q1[1][v] + Q2[1][v] * LO_INV;
          red[wave][2][v][lane] = P1[2][v] + P2[2][v] * LO_INV;
          red[wave][3][v][lane] = Q1[2][v] + Q2[2][v] * LO_INV;
        }
        __syncthreads();
#pragma unroll
        for (int u = 0; u < 2; ++u) {
          int v = khalf * 2 + u;
          int si = s0 + (lane >> 4) * 4 + v;
          float sr = red[wave][0][v][lane] + red[w2i][0][v][lane] + bi_r + bh_r;
          float sz = red[wave][1][v][lane] + red[w2i][1][v][lane] + bi_z + bh_z;
          float xn = red[wave][2][v][lane] + red[w2i][2][v][lane] + bi_n;
          float hn = red[wave][3][v][lane] + red[w2i][3][v][lane] + bh_n;
          float r = 1.f / (1.f + expf(-sr));
          float z = 1.f / (1.f + expf(-sz));
          float n = tanhf(xn + r * hn);
          float hnew = (1.f - z) * n + z * hp_[u];
          size_t ow = (size_t)wo * 65536 + (size_t)si * 256 + jj;
          h1f[ow] = hnew;  // self-owned: plain store
          f16 hh = (f16)hnew;
          f16 hl = (f16)((hnew - (float)hh) * LO_SCALE);
          cstore_pair(h1h, h1l, ow, lane, hh, hl);
        }
      }
      if (iv < 250) grpbar(bar, mg, rank, iv, true);
    }
  }
}

// ===================== head =====================
__global__ __launch_bounds__(256) void k_head(
    const f16* __restrict__ hh, const f16* __restrict__ hl,
    const f16* __restrict__ Wah, const f16* __restrict__ Wal,
    const f16* __restrict__ Wfh, const f16* __restrict__ Wfl,
    const float* __restrict__ ba, const float* __restrict__ bf,
    float* __restrict__ att, float* __restrict__ logit) {
  const int mat = blockIdx.z;
  const f16* Wh = mat ? Wfh : Wah;
  const f16* Wl = mat ? Wfl : Wal;
  const float* bias = mat ? bf : ba;
  float* outp = mat ? logit : att;
  const int n0 = blockIdx.x * 64;
  const int lane = threadIdx.x & 63, wave = threadIdx.x >> 6;
  const int s0 = blockIdx.y * 64 + wave * 16;
  const int fr = lane & 15, fk = (lane >> 4) * 8;
  const f16* ahp = hh + (size_t)(s0 + fr) * 256 + fk;
  const f16* alp = hl + (size_t)(s0 + fr) * 256 + fk;
  const f32x4 z4 = {0.f, 0.f, 0.f, 0.f};
  f32x4 c1[4], c2[4];
#pragma unroll
  for (int ni = 0; ni < 4; ++ni) {
    c1[ni] = z4;
    c2[ni] = z4;
  }
#pragma unroll 2
  for (int k = 0; k < 256; k += 32) {
    f16x8 xh = *(const f16x8*)(ahp + k);
    f16x8 xl = *(const f16x8*)(alp + k);
#pragma unroll
    for (int ni = 0; ni < 4; ++ni) {
      const f16* bp = Wh + (size_t)(n0 + ni * 16 + fr) * 256 + k + fk;
      const f16* bq = Wl + (size_t)(n0 + ni * 16 + fr) * 256 + k + fk;
      f16x8 bh = *(const f16x8*)bp;
      f16x8 bl = *(const f16x8*)bq;
      c1[ni] = MFMA(xh, bh, c1[ni]);
      c2[ni] = MFMA(xl, bh, c2[ni]);
      c2[ni] = MFMA(xh, bl, c2[ni]);
    }
  }
#pragma unroll
  for (int ni = 0; ni < 4; ++ni) {
    int c = n0 + ni * 16 + fr;
    float b = bias[c];
#pragma unroll
    for (int v = 0; v < 4; ++v) {
      int si = s0 + (lane >> 4) * 4 + v;
      float val = c1[ni][v] + c2[ni][v] * LO_INV + b;
      float sg = 1.f / (1.f + expf(-val));
      outp[(size_t)si * 2048 + c] = mat ? val * sg : sg;
    }
  }
}

// ===================== portfolio: topk + softmax-mask-norm + rebalance ======
__global__ __launch_bounds__(256) void k_port(const float* __restrict__ att,
                                              const float* __restrict__ logit,
                                              float* __restrict__ out) {
  __shared__ float av[2048];
  __shared__ float wv[2048];
  __shared__ float ov[2048];
  __shared__ unsigned char sel[2048];
  __shared__ float ra[4], rb[4], rc[4];
  __shared__ float rvv[4];
  __shared__ int rii[4];

  const int s = blockIdx.x;
  const int tid = threadIdx.x;
  const int lane = tid & 63, wave = tid >> 6;
  const float UBv = 0.1f;

  float lmax = -INFINITY;
#pragma unroll
  for (int j = 0; j < 8; ++j) {
    int i = tid + j * 256;
    av[i] = att[(size_t)s * 2048 + i];
    float l = logit[(size_t)s * 2048 + i];
    wv[i] = l;
    sel[i] = 0;
    lmax = fmaxf(lmax, l);
  }
#pragma unroll
  for (int off = 32; off; off >>= 1) lmax = fmaxf(lmax, __shfl_down(lmax, off, 64));
  if (lane == 0) ra[wave] = lmax;
  __syncthreads();
  float M = fmaxf(fmaxf(ra[0], ra[1]), fmaxf(ra[2], ra[3]));
  float es = 0.f;
#pragma unroll
  for (int j = 0; j < 8; ++j) {
    int i = tid + j * 256;
    float e = expf(wv[i] - M);
    wv[i] = e;
    es += e;
  }
#pragma unroll
  for (int off = 32; off; off >>= 1) es += __shfl_down(es, off, 64);
  __syncthreads();
  if (lane == 0) ra[wave] = es;
  __syncthreads();
  float S = ra[0] + ra[1] + ra[2] + ra[3];
#pragma unroll
  for (int j = 0; j < 8; ++j) {
    int i = tid + j * 256;
    wv[i] = wv[i] / S;
  }
  __syncthreads();

  for (int it = 0; it < 50; ++it) {
    float bv = -INFINITY;
    int bi = 0x7fffffff;
#pragma unroll
    for (int j = 0; j < 8; ++j) {
      int i = tid + j * 256;
      float v = av[i];
      if (v > bv || (v == bv && i < bi)) {
        bv = v;
        bi = i;
      }
    }
#pragma unroll
    for (int off = 32; off; off >>= 1) {
      float o2 = __shfl_down(bv, off, 64);
      int oi = __shfl_down(bi, off, 64);
      if (o2 > bv || (o2 == bv && oi < bi)) {
        bv = o2;
        bi = oi;
      }
    }
    if (lane == 0) {
      rvv[wave] = bv;
      rii[wave] = bi;
    }
    __syncthreads();
    if (tid == 0) {
      float fb = rvv[0];
      int fi = rii[0];
#pragma unroll
      for (int w2 = 1; w2 < 4; ++w2)
        if (rvv[w2] > fb || (rvv[w2] == fb && rii[w2] < fi)) {
          fb = rvv[w2];
          fi = rii[w2];
        }
      av[fi] = -INFINITY;
      sel[fi] = 1;
    }
    __syncthreads();
  }

  float ms = 0.f;
#pragma unroll
  for (int j = 0; j < 8; ++j) {
    int i = tid + j * 256;
    float m_ = sel[i] ? wv[i] : 0.f;
    wv[i] = m_;
    ms += m_;
  }
#pragma unroll
  for (int off = 32; off; off >>= 1) ms += __shfl_down(ms, off, 64);
  if (lane == 0) rb[wave] = ms;
  __syncthreads();
  float MS = rb[0] + rb[1] + rb[2] + rb[3];
  float den0 = MS + 1e-8f;
#pragma unroll
  for (int j = 0; j < 8; ++j) {
    int i = tid + j * 256;
    float w0 = wv[i] / den0;
    ov[i] = w0;
    sel[i] = (w0 > 0.f) ? 1 : 0;
    wv[i] = fminf(fmaxf(w0, 0.f), UBv);
  }

  bool done = false;
  for (int it = 0; it < 32; ++it) {
    __syncthreads();
    float lft = 0.f, ns = 0.f, hn = 0.f;
#pragma unroll
    for (int j = 0; j < 8; ++j) {
      int i = tid + j * 256;
      float wi = wv[i];
      bool nm = sel[i] && (wi != UBv);
      lft += ov[i] - wi;
      if (nm) {
        ns += wi;
        hn = 1.f;
      }
    }
#pragma unroll
    for (int off = 32; off; off >>= 1) {
      lft += __shfl_down(lft, off, 64);
      ns += __shfl_down(ns, off, 64);
      hn += __shfl_down(hn, off, 64);
    }
    if (lane == 0) {
      ra[wave] = lft;
      rb[wave] = ns;
      rc[wave] = hn;
    }
    __syncthreads();
    float LFT = ra[0] + ra[1] + ra[2] + ra[3];
    float NS = rb[0] + rb[1] + rb[2] + rb[3];
    bool has_nom = (rc[0] + rc[1] + rc[2] + rc[3]) > 0.f;
    bool upd = (!done) && has_nom;
    float dn = (NS == 0.f) ? 1.f : NS;
    bool over = false;
    if (upd) {
      float ovf = 0.f;
#pragma unroll
      for (int j = 0; j < 8; ++j) {
        int i = tid + j * 256;
        float wi = wv[i];
        bool nm = sel[i] && (wi != UBv);
        float w1 = wi + (nm ? (LFT * wi) / dn : 0.f);
        wv[i] = w1;
        ov[i] = w1;
        if (w1 > UBv) ovf = 1.f;
      }
#pragma unroll
      for (int off = 32; off; off >>= 1) ovf += __shfl_down(ovf, off, 64);
      __syncthreads();
      if (lane == 0) rc[wave] = ovf;
      __syncthreads();
      over = (rc[0] + rc[1] + rc[2] + rc[3]) > 0.f;
      if (over) {
#pragma unroll
        for (int j = 0; j < 8; ++j) {
          int i = tid + j * 256;
          wv[i] = fminf(fmaxf(wv[i], 0.f), UBv);
        }
      }
    }
    done = done || (!has_nom) || (upd && !over);
  }
  __syncthreads();
#pragma unroll
  for (int j = 0; j < 8; ++j) {
    int i = tid + j * 256;
    out[(size_t)s * 2048 + i] = wv[i];
  }
}

// ===================== launch =====================
extern "C" void kernel_launch(void* const* d_in, const int* in_sizes, int n_in,
                              void* d_out, int out_size, void* d_ws,
                              size_t ws_size, hipStream_t stream) {
  (void)in_sizes;
  (void)n_in;
  (void)out_size;
  (void)ws_size;
  const float* x = (const float*)d_in[0];
  const float* Wih0 = (const float*)d_in[1];
  const float* Whh0 = (const float*)d_in[2];
  const float* bih0 = (const float*)d_in[3];
  const float* bhh0 = (const float*)d_in[4];
  const float* Wih1 = (const float*)d_in[5];
  const float* Whh1 = (const float*)d_in[6];
  const float* bih1 = (const float*)d_in[7];
  const float* bhh1 = (const float*)d_in[8];
  const float* Wa = (const float*)d_in[9];
  const float* ba = (const float*)d_in[10];
  const float* Wf = (const float*)d_in[11];
  const float* bf = (const float*)d_in[12];

  char* p = (char*)d_ws;
  auto alloc = [&](size_t bytes) {
    char* q = p;
    p += (bytes + 255) & ~(size_t)255;
    return q;
  };
  float* XG = (float*)alloc((size_t)250 * 256 * 768 * 4);  // 196.6 MB
  f16* Whh0h = (f16*)alloc(768 * 256 * 2);
  f16* Whh0l = (f16*)alloc(768 * 256 * 2);
  f16* Wih1h = (f16*)alloc(768 * 256 * 2);
  f16* Wih1l = (f16*)alloc(768 * 256 * 2);
  f16* Whh1h = (f16*)alloc(768 * 256 * 2);
  f16* Whh1l = (f16*)alloc(768 * 256 * 2);
  f16* Wah = (f16*)alloc(2048 * 256 * 2);
  f16* Wal = (f16*)alloc(2048 * 256 * 2);
  f16* Wfh = (f16*)alloc(2048 * 256 * 2);
  f16* Wfl = (f16*)alloc(2048 * 256 * 2);
  float* h0f = (float*)alloc(2 * 65536 * 4);
  f16* h0h = (f16*)alloc(2 * 65536 * 2);
  f16* h0l = (f16*)alloc(2 * 65536 * 2);
  float* h1f = (float*)alloc(2 * 65536 * 4);
  f16* h1h = (f16*)alloc(2 * 65536 * 2);
  f16* h1l = (f16*)alloc(2 * 65536 * 2);
  float* attb = (float*)alloc((size_t)256 * 2048 * 4);
  float* logitb = (float*)alloc((size_t)256 * 2048 * 4);
  int* bar = (int*)alloc(64 * 1024);  // 4 groups x 64 slots x 256B

  // zero h states (contiguous) + barrier flags
  hipMemsetAsync(h0f, 0, (size_t)2 * 65536 * 8 * 2, stream);
  hipMemsetAsync(bar, 0, 64 * 1024, stream);

  k_split<<<192, 256, 0, stream>>>(Whh0, Whh0h, Whh0l, 768 * 256 / 4);
  k_split<<<192, 256, 0, stream>>>(Wih1, Wih1h, Wih1l, 768 * 256 / 4);
  k_split<<<192, 256, 0, stream>>>(Whh1, Whh1h, Whh1l, 768 * 256 / 4);
  k_split<<<512, 256, 0, stream>>>(Wa, Wah, Wal, 2048 * 256 / 4);
  k_split<<<512, 256, 0, stream>>>(Wf, Wfh, Wfl, 2048 * 256 / 4);

  k_gemm_xg0<<<dim3(500, 12), 256, 0, stream>>>(x, Wih0, bih0, XG);

  k_gru_persist<<<NBLK_GRU, 256, 0, stream>>>(
      XG, Whh0h, Whh0l, Wih1h, Wih1l, Whh1h, Whh1l, bhh0, bih1, bhh1, h0f, h0h,
      h0l, h1f, h1h, h1l, bar);

  // final h1 state (t=249) lives in slot 1
  k_head<<<dim3(32, 4, 2), 256, 0, stream>>>(h1h + 65536, h1l + 65536, Wah, Wal,
                                             Wfh, Wfl, ba, bf, attb, logitb);
  k_port<<<256, 256, 0, stream>>>(attb, logitb, (float*)d_out);
}